// Round 3
// baseline (262.846 us; speedup 1.0000x reference)
//
#include <hip/hip_runtime.h>
#include <math.h>

// Problem constants (fixed by setup_inputs).
#define B_ 2
#define V_ 4
#define F_ 32
#define H_ 256
#define W_ 256
#define N_ 262144   // 64*64*64, G=1

// ---------------------------------------------------------------------------
// fp32 projection, bit-mirroring the numpy-float32 reference op sequence:
//   uvd_i = (((KRT[i][0]*x + KRT[i][1]*y) + KRT[i][2]*z) + KRT[i][3])
//   u = ((2*u0)/u2)/255 - 1 ;  px = ((u+1)*256 - 1)*0.5
// No FMA contraction (numpy rounds each mul/add separately).
// ---------------------------------------------------------------------------
__device__ __forceinline__ void project_f(const float* k, float x, float y,
                                          float z, float& px, float& py) {
#pragma clang fp contract(off)
    float u0 = k[0] * x;  u0 = u0 + k[1] * y;  u0 = u0 + k[2]  * z;  u0 = u0 + k[3];
    float u1 = k[4] * x;  u1 = u1 + k[5] * y;  u1 = u1 + k[6]  * z;  u1 = u1 + k[7];
    float u2 = k[8] * x;  u2 = u2 + k[9] * y;  u2 = u2 + k[10] * z;  u2 = u2 + k[11];
    float uu = 2.0f * u0; uu = uu / u2; uu = uu / 255.0f; uu = uu - 1.0f;
    float vv = 2.0f * u1; vv = vv / u2; vv = vv / 255.0f; vv = vv - 1.0f;
    float tx = uu + 1.0f; tx = tx * 256.0f; tx = tx - 1.0f; px = tx * 0.5f;
    float ty = vv + 1.0f; ty = ty * 256.0f; ty = ty - 1.0f; py = ty * 0.5f;
}

// Bilinear corner weights (fp32, no contraction) + clamped indices;
// zero-padding semantics (per-corner validity, clip-then-cast).
__device__ __forceinline__ void corner_weights_f(float px, float py,
                                                 float& w00, float& w01,
                                                 float& w10, float& w11,
                                                 int& x0, int& x1,
                                                 int& y0, int& y1) {
#pragma clang fp contract(off)
    float x0f = floorf(px), y0f = floorf(py);
    float wx1 = px - x0f, wx0 = 1.0f - wx1;
    float wy1 = py - y0f, wy0 = 1.0f - wy1;
    bool vx0 = (x0f >= 0.0f)  && (x0f <= 255.0f);
    bool vx1 = (x0f >= -1.0f) && (x0f <= 254.0f);   // x0f+1 in [0,255]
    bool vy0 = (y0f >= 0.0f)  && (y0f <= 255.0f);
    bool vy1 = (y0f >= -1.0f) && (y0f <= 254.0f);
    w00 = (vx0 && vy0) ? wx0 * wy0 : 0.0f;
    w01 = (vx1 && vy0) ? wx1 * wy0 : 0.0f;
    w10 = (vx0 && vy1) ? wx0 * wy1 : 0.0f;
    w11 = (vx1 && vy1) ? wx1 * wy1 : 0.0f;
    x0 = (int)fminf(fmaxf(x0f,        0.0f), 255.0f);
    x1 = (int)fminf(fmaxf(x0f + 1.0f, 0.0f), 255.0f);
    y0 = (int)fminf(fmaxf(y0f,        0.0f), 255.0f);
    y1 = (int)fminf(fmaxf(y0f + 1.0f, 0.0f), 255.0f);
}

// ---------------------------------------------------------------------------
// K1: transpose feat (B,V,F,H,W) -> feat_t (B,V,H,W,F)  [channel-last]
// One block per (bv, y) row. 256 threads. No FP math.
// ---------------------------------------------------------------------------
__global__ __launch_bounds__(256) void transpose_kernel(
        const float* __restrict__ feat, float* __restrict__ ft) {
    __shared__ float lds[32][257];
    int blk = blockIdx.x;
    int bv = blk >> 8;        // 0..7
    int y  = blk & 255;
    int t  = threadIdx.x;     // = x in read phase

    size_t base = (size_t)bv * (32 * 65536) + (size_t)y * 256;
#pragma unroll
    for (int f = 0; f < 32; f++) {
        lds[f][t] = feat[base + (size_t)f * 65536 + t];
    }
    __syncthreads();

    size_t obase = ((size_t)bv * 256 + y) * 8192;   // (bv*H + y) * W * F
#pragma unroll
    for (int k = 0; k < 32; k++) {
        int idx = k * 256 + t;            // idx = x*32 + f
        ft[obase + idx] = lds[idx & 31][idx >> 5];
    }
}

// ---------------------------------------------------------------------------
// K2: main sampler using channel-last feat_t.
// Block = 256 threads handles 64 consecutive points of one batch.
//   Phase A: fp32 KRT (LDS, sequential j order) + per-(view,point) coords.
//   Phase B: 32-lane group per point-slot; lane f = channel f. Each corner
//            load is a contiguous, 128B-aligned 32-float segment.
//   Phase C: LDS transpose -> fully coalesced channel-major output writes.
// All mirrored math: fp32, contract(off), reference op order.
// ---------------------------------------------------------------------------
__global__ __launch_bounds__(256) void sample_kernel(
        const float* __restrict__ ft, const float* __restrict__ RTs,
        const float* __restrict__ Ks, const float* __restrict__ grids,
        float* __restrict__ out) {
    __shared__ float lkrt[4][12];
    __shared__ float sx[4][64];
    __shared__ float sy[4][64];
    __shared__ float smean[32][65];
    __shared__ float svar[32][65];

    int t   = threadIdx.x;
    int blk = blockIdx.x;
    int b   = blk >> 12;              // 4096 blocks per batch
    int n0  = (blk & 4095) << 6;      // 64 points per block

    // KRT = Ks @ RTs (fp32, sequential j accumulation, no fma).
    if (t < 48) {
#pragma clang fp contract(off)
        int v = t / 12, ij = t % 12, i = ij >> 2, j = ij & 3;
        int bv = b * 4 + v;
        const float* K = Ks + bv * 9;
        const float* R = RTs + bv * 12;
        float acc = K[i * 3 + 0] * R[0 * 4 + j];
        acc = acc + K[i * 3 + 1] * R[1 * 4 + j];
        acc = acc + K[i * 3 + 2] * R[2 * 4 + j];
        lkrt[v][ij] = acc;
    }
    __syncthreads();

    // Phase A: coords for all (view, point) pairs: 4*64 = 256 tasks.
    {
        int v = t >> 6, p = t & 63;
        int n = n0 + p;
        size_t gb = (size_t)b * 3 * N_ + n;
        float x = grids[gb];
        float y = grids[gb + N_];
        float z = grids[gb + 2 * (size_t)N_];
        float px, py;
        project_f(lkrt[v], x, y, z, px, py);
        sx[v][p] = px;
        sy[v][p] = py;
    }
    __syncthreads();

    // Phase B: lane f handles channel f; 32-lane group g handles 8 points.
    int f = t & 31, g = t >> 5;       // g in 0..7
    for (int i = 0; i < 8; i++) {
#pragma clang fp contract(off)
        int p = g * 8 + i;
        float accm = 0.0f, accq = 0.0f;
#pragma unroll
        for (int v = 0; v < 4; v++) {
            float px = sx[v][p], py = sy[v][p];
            float w00, w01, w10, w11;
            int x0, x1, y0, y1;
            corner_weights_f(px, py, w00, w01, w10, w11, x0, x1, y0, y1);
            if (w00 + w01 + w10 + w11 != 0.0f) {
                size_t rb = ((size_t)(b * 4 + v)) << 16;  // bv * H * W pixels
                size_t i00 = ((rb + (size_t)(y0 * 256 + x0)) << 5) + f;
                size_t i01 = ((rb + (size_t)(y0 * 256 + x1)) << 5) + f;
                size_t i10 = ((rb + (size_t)(y1 * 256 + x0)) << 5) + f;
                size_t i11 = ((rb + (size_t)(y1 * 256 + x1)) << 5) + f;
                // s = ((g00 + g01) + g10) + g11, each gij = feat*w rounded.
                float s = ft[i00] * w00;
                s = s + ft[i01] * w01;
                s = s + ft[i10] * w10;
                s = s + ft[i11] * w11;
                accm = accm + s;
                float q = s * s;
                accq = accq + q;
            }
        }
        float mean = accm * 0.25f;
        float msq  = accq * 0.25f;
        float mean2 = mean * mean;
        float var   = msq - mean2;
        smean[f][p] = mean;
        svar[f][p]  = var;
    }
    __syncthreads();

    // Phase C: coalesced writes. out[(b*64 + c)*N + n0 + j].
    int j = t & 63, c4 = t >> 6;
    size_t ob = (size_t)b * 64 * N_ + n0 + j;
#pragma unroll
    for (int k = 0; k < 16; k++) {
        int c = k * 4 + c4;
        float val = (c < 32) ? smean[c][j] : svar[c - 32][j];
        out[ob + (size_t)c * N_] = val;
    }
}

// ---------------------------------------------------------------------------
// Fallback (ws too small): thread per (b, f, n), gathers from native layout.
// Same mirrored fp32 math.
// ---------------------------------------------------------------------------
__global__ __launch_bounds__(256) void naive_kernel(
        const float* __restrict__ feat, const float* __restrict__ RTs,
        const float* __restrict__ Ks, const float* __restrict__ grids,
        float* __restrict__ out) {
#pragma clang fp contract(off)
    size_t idx = (size_t)blockIdx.x * 256 + threadIdx.x;  // (b*32+f)*N + n
    int n  = (int)(idx & (N_ - 1));
    int bf = (int)(idx >> 18);
    int f  = bf & 31, b = bf >> 5;

    size_t gb = (size_t)b * 3 * N_ + n;
    float x = grids[gb];
    float y = grids[gb + N_];
    float z = grids[gb + 2 * (size_t)N_];

    float accm = 0.0f, accq = 0.0f;
    for (int v = 0; v < 4; v++) {
        int bv = b * 4 + v;
        const float* K = Ks + bv * 9;
        const float* R = RTs + bv * 12;
        float k[12];
#pragma unroll
        for (int i = 0; i < 3; i++)
#pragma unroll
            for (int j = 0; j < 4; j++) {
                float acc = K[i * 3 + 0] * R[0 * 4 + j];
                acc = acc + K[i * 3 + 1] * R[1 * 4 + j];
                acc = acc + K[i * 3 + 2] * R[2 * 4 + j];
                k[i * 4 + j] = acc;
            }
        float px, py;
        project_f(k, x, y, z, px, py);
        float w00, w01, w10, w11;
        int x0, x1, y0, y1;
        corner_weights_f(px, py, w00, w01, w10, w11, x0, x1, y0, y1);
        if (w00 + w01 + w10 + w11 != 0.0f) {
            size_t fb = ((size_t)bv * 32 + f) * 65536;
            float s = feat[fb + y0 * 256 + x0] * w00;
            s = s + feat[fb + y0 * 256 + x1] * w01;
            s = s + feat[fb + y1 * 256 + x0] * w10;
            s = s + feat[fb + y1 * 256 + x1] * w11;
            accm = accm + s;
            float q = s * s;
            accq = accq + q;
        }
    }
    float mean = accm * 0.25f;
    float msq  = accq * 0.25f;
    float mean2 = mean * mean;
    float var   = msq - mean2;
    size_t ob = ((size_t)b * 64 + f) * N_ + n;
    out[ob] = mean;
    out[ob + 32 * (size_t)N_] = var;
}

// ---------------------------------------------------------------------------
extern "C" void kernel_launch(void* const* d_in, const int* in_sizes, int n_in,
                              void* d_out, int out_size, void* d_ws, size_t ws_size,
                              hipStream_t stream) {
    const float* feat  = (const float*)d_in[0];
    const float* RTs   = (const float*)d_in[1];
    const float* Ks    = (const float*)d_in[2];
    const float* grids = (const float*)d_in[3];
    float* out = (float*)d_out;

    const size_t ft_bytes = (size_t)B_ * V_ * H_ * W_ * F_ * sizeof(float); // 64 MiB
    if (ws_size >= ft_bytes) {
        float* ft = (float*)d_ws;
        transpose_kernel<<<B_ * V_ * H_, 256, 0, stream>>>(feat, ft);
        sample_kernel<<<(B_ * N_) / 64, 256, 0, stream>>>(ft, RTs, Ks, grids, out);
    } else {
        naive_kernel<<<(B_ * F_ * N_) / 256, 256, 0, stream>>>(feat, RTs, Ks, grids, out);
    }
}

// Round 4
// 233.058 us; speedup vs baseline: 1.1278x; 1.1278x over previous
//
#include <hip/hip_runtime.h>
#include <math.h>

// Problem constants (fixed by setup_inputs).
#define B_ 2
#define V_ 4
#define F_ 32
#define H_ 256
#define W_ 256
#define N_ 262144   // 64*64*64, G=1

// ---------------------------------------------------------------------------
// fp32 projection, bit-mirroring the numpy-float32 reference op sequence.
// No FMA contraction (numpy rounds each mul/add separately). UNCHANGED vs R3.
// ---------------------------------------------------------------------------
__device__ __forceinline__ void project_f(const float* k, float x, float y,
                                          float z, float& px, float& py) {
#pragma clang fp contract(off)
    float u0 = k[0] * x;  u0 = u0 + k[1] * y;  u0 = u0 + k[2]  * z;  u0 = u0 + k[3];
    float u1 = k[4] * x;  u1 = u1 + k[5] * y;  u1 = u1 + k[6]  * z;  u1 = u1 + k[7];
    float u2 = k[8] * x;  u2 = u2 + k[9] * y;  u2 = u2 + k[10] * z;  u2 = u2 + k[11];
    float uu = 2.0f * u0; uu = uu / u2; uu = uu / 255.0f; uu = uu - 1.0f;
    float vv = 2.0f * u1; vv = vv / u2; vv = vv / 255.0f; vv = vv - 1.0f;
    float tx = uu + 1.0f; tx = tx * 256.0f; tx = tx - 1.0f; px = tx * 0.5f;
    float ty = vv + 1.0f; ty = ty * 256.0f; ty = ty - 1.0f; py = ty * 0.5f;
}

// Bilinear corner weights (fp32, no contraction) + clamped indices. UNCHANGED.
__device__ __forceinline__ void corner_weights_f(float px, float py,
                                                 float& w00, float& w01,
                                                 float& w10, float& w11,
                                                 int& x0, int& x1,
                                                 int& y0, int& y1) {
#pragma clang fp contract(off)
    float x0f = floorf(px), y0f = floorf(py);
    float wx1 = px - x0f, wx0 = 1.0f - wx1;
    float wy1 = py - y0f, wy0 = 1.0f - wy1;
    bool vx0 = (x0f >= 0.0f)  && (x0f <= 255.0f);
    bool vx1 = (x0f >= -1.0f) && (x0f <= 254.0f);   // x0f+1 in [0,255]
    bool vy0 = (y0f >= 0.0f)  && (y0f <= 255.0f);
    bool vy1 = (y0f >= -1.0f) && (y0f <= 254.0f);
    w00 = (vx0 && vy0) ? wx0 * wy0 : 0.0f;
    w01 = (vx1 && vy0) ? wx1 * wy0 : 0.0f;
    w10 = (vx0 && vy1) ? wx0 * wy1 : 0.0f;
    w11 = (vx1 && vy1) ? wx1 * wy1 : 0.0f;
    x0 = (int)fminf(fmaxf(x0f,        0.0f), 255.0f);
    x1 = (int)fminf(fmaxf(x0f + 1.0f, 0.0f), 255.0f);
    y0 = (int)fminf(fmaxf(y0f,        0.0f), 255.0f);
    y1 = (int)fminf(fmaxf(y0f + 1.0f, 0.0f), 255.0f);
}

// ---------------------------------------------------------------------------
// K1: transpose feat (B,V,F,H,W) -> feat_t (B,V,H,W,F)  [channel-last]
// One block per (bv, y) row. 256 threads. HBM-streaming-bound; unchanged.
// ---------------------------------------------------------------------------
__global__ __launch_bounds__(256) void transpose_kernel(
        const float* __restrict__ feat, float* __restrict__ ft) {
    __shared__ float lds[32][257];
    int blk = blockIdx.x;
    int bv = blk >> 8;        // 0..7
    int y  = blk & 255;
    int t  = threadIdx.x;     // = x in read phase

    size_t base = (size_t)bv * (32 * 65536) + (size_t)y * 256;
#pragma unroll
    for (int f = 0; f < 32; f++) {
        lds[f][t] = feat[base + (size_t)f * 65536 + t];
    }
    __syncthreads();

    size_t obase = ((size_t)bv * 256 + y) * 8192;   // (bv*H + y) * W * F
#pragma unroll
    for (int k = 0; k < 32; k++) {
        int idx = k * 256 + t;            // idx = x*32 + f
        ft[obase + idx] = lds[idx & 31][idx >> 5];
    }
}

// ---------------------------------------------------------------------------
// K2: sampler. Block = 256 threads, 64 points of one batch.
//   Phase A: one thread per (view,point) task (256 tasks): fp32 projection +
//            corner weights + BYTE offsets -> LDS (float4/uint4 packed).
//            Weight math computed ONCE per task instead of once per 32-lane
//            group per task (the R3 VALU hot spot, VALUBusy 93-98%).
//   Phase B: 8 lanes per point, float4 per lane = 4 channels. Per (view,
//            8 points) per wave: 2 broadcast ds_read_b128 + 4 dwordx4 loads.
//            Exec-masked skip keeps OOB semantics + saves L2 traffic.
//   Phase C: LDS transpose -> coalesced channel-major output writes.
// All mirrored FP chains bit-identical to the passing R3 kernel.
// ---------------------------------------------------------------------------
__global__ __launch_bounds__(256) void sample_kernel(
        const float* __restrict__ ft, const float* __restrict__ RTs,
        const float* __restrict__ Ks, const float* __restrict__ grids,
        float* __restrict__ out) {
    __shared__ float lkrt[4][12];
    __shared__ __align__(16) float        w4lds[4][64][4];
    __shared__ __align__(16) unsigned int o4lds[4][64][4];
    __shared__ float smean[32][65];
    __shared__ float svar[32][65];

    int t   = threadIdx.x;
    int blk = blockIdx.x;
    int b   = blk >> 12;              // 4096 blocks per batch
    int n0  = (blk & 4095) << 6;      // 64 points per block

    // KRT = Ks @ RTs (fp32, sequential j accumulation, no fma).
    if (t < 48) {
#pragma clang fp contract(off)
        int v = t / 12, ij = t % 12, i = ij >> 2, j = ij & 3;
        int bv = b * 4 + v;
        const float* K = Ks + bv * 9;
        const float* R = RTs + bv * 12;
        float acc = K[i * 3 + 0] * R[0 * 4 + j];
        acc = acc + K[i * 3 + 1] * R[1 * 4 + j];
        acc = acc + K[i * 3 + 2] * R[2 * 4 + j];
        lkrt[v][ij] = acc;
    }
    __syncthreads();

    // Phase A: weights + byte offsets for all 256 (view,point) tasks.
    {
        int v = t >> 6, p = t & 63;
        int n = n0 + p;
        size_t gb = (size_t)b * 3 * N_ + n;
        float x = grids[gb];
        float y = grids[gb + N_];
        float z = grids[gb + 2 * (size_t)N_];
        float px, py;
        project_f(lkrt[v], x, y, z, px, py);
        float w00, w01, w10, w11;
        int x0, x1, y0, y1;
        corner_weights_f(px, py, w00, w01, w10, w11, x0, x1, y0, y1);
        w4lds[v][p][0] = w00;
        w4lds[v][p][1] = w01;
        w4lds[v][p][2] = w10;
        w4lds[v][p][3] = w11;
        // byte offset into ft: pixel*(32 ch * 4 B) = pixel << 7
        unsigned int rb = (unsigned int)(b * 4 + v) << 16;   // bv * H * W
        o4lds[v][p][0] = (rb + (unsigned int)(y0 * 256 + x0)) << 7;
        o4lds[v][p][1] = (rb + (unsigned int)(y0 * 256 + x1)) << 7;
        o4lds[v][p][2] = (rb + (unsigned int)(y1 * 256 + x0)) << 7;
        o4lds[v][p][3] = (rb + (unsigned int)(y1 * 256 + x1)) << 7;
    }
    __syncthreads();

    // Phase B: subgroup = 8 lanes per point; lane ln covers channels 4ln..4ln+3.
    int ln = t & 7;                   // channel quad within point
    int sg = t >> 3;                  // 0..31: point slot within pass
    const char* ftb = (const char*)ft;
    unsigned int lnoff = (unsigned int)(ln << 4);   // ln * 16 bytes

    for (int pass = 0; pass < 2; pass++) {
#pragma clang fp contract(off)
        int p = sg + pass * 32;
        float am0 = 0.0f, am1 = 0.0f, am2 = 0.0f, am3 = 0.0f;
        float aq0 = 0.0f, aq1 = 0.0f, aq2 = 0.0f, aq3 = 0.0f;
#pragma unroll
        for (int v = 0; v < 4; v++) {
            const float4 w = *(const float4*)w4lds[v][p];   // broadcast b128
            const uint4  o = *(const uint4*) o4lds[v][p];   // broadcast b128
            float wsum = w.x + w.y;  wsum = wsum + w.z;  wsum = wsum + w.w;
            if (wsum != 0.0f) {
                float4 c00 = *(const float4*)(ftb + (o.x + lnoff));
                float4 c01 = *(const float4*)(ftb + (o.y + lnoff));
                float4 c10 = *(const float4*)(ftb + (o.z + lnoff));
                float4 c11 = *(const float4*)(ftb + (o.w + lnoff));
                // s = ((f00*w00 + f01*w01) + f10*w10) + f11*w11 per channel
                float s0 = c00.x * w.x; s0 = s0 + c01.x * w.y; s0 = s0 + c10.x * w.z; s0 = s0 + c11.x * w.w;
                float s1 = c00.y * w.x; s1 = s1 + c01.y * w.y; s1 = s1 + c10.y * w.z; s1 = s1 + c11.y * w.w;
                float s2 = c00.z * w.x; s2 = s2 + c01.z * w.y; s2 = s2 + c10.z * w.z; s2 = s2 + c11.z * w.w;
                float s3 = c00.w * w.x; s3 = s3 + c01.w * w.y; s3 = s3 + c10.w * w.z; s3 = s3 + c11.w * w.w;
                am0 = am0 + s0;  am1 = am1 + s1;  am2 = am2 + s2;  am3 = am3 + s3;
                float q0 = s0 * s0, q1 = s1 * s1, q2 = s2 * s2, q3 = s3 * s3;
                aq0 = aq0 + q0;  aq1 = aq1 + q1;  aq2 = aq2 + q2;  aq3 = aq3 + q3;
            }
        }
        float m0 = am0 * 0.25f, m1 = am1 * 0.25f, m2 = am2 * 0.25f, m3 = am3 * 0.25f;
        float e0 = aq0 * 0.25f, e1 = aq1 * 0.25f, e2 = aq2 * 0.25f, e3 = aq3 * 0.25f;
        float mm0 = m0 * m0, mm1 = m1 * m1, mm2 = m2 * m2, mm3 = m3 * m3;
        int c = ln << 2;
        smean[c + 0][p] = m0;  svar[c + 0][p] = e0 - mm0;
        smean[c + 1][p] = m1;  svar[c + 1][p] = e1 - mm1;
        smean[c + 2][p] = m2;  svar[c + 2][p] = e2 - mm2;
        smean[c + 3][p] = m3;  svar[c + 3][p] = e3 - mm3;
    }
    __syncthreads();

    // Phase C: coalesced writes. out[(b*64 + c)*N + n0 + j].
    int j = t & 63, c4 = t >> 6;
    size_t ob = (size_t)b * 64 * N_ + n0 + j;
#pragma unroll
    for (int k = 0; k < 16; k++) {
        int c = k * 4 + c4;
        float val = (c < 32) ? smean[c][j] : svar[c - 32][j];
        out[ob + (size_t)c * N_] = val;
    }
}

// ---------------------------------------------------------------------------
// Fallback (ws too small): thread per (b, f, n), gathers from native layout.
// ---------------------------------------------------------------------------
__global__ __launch_bounds__(256) void naive_kernel(
        const float* __restrict__ feat, const float* __restrict__ RTs,
        const float* __restrict__ Ks, const float* __restrict__ grids,
        float* __restrict__ out) {
#pragma clang fp contract(off)
    size_t idx = (size_t)blockIdx.x * 256 + threadIdx.x;  // (b*32+f)*N + n
    int n  = (int)(idx & (N_ - 1));
    int bf = (int)(idx >> 18);
    int f  = bf & 31, b = bf >> 5;

    size_t gb = (size_t)b * 3 * N_ + n;
    float x = grids[gb];
    float y = grids[gb + N_];
    float z = grids[gb + 2 * (size_t)N_];

    float accm = 0.0f, accq = 0.0f;
    for (int v = 0; v < 4; v++) {
        int bv = b * 4 + v;
        const float* K = Ks + bv * 9;
        const float* R = RTs + bv * 12;
        float k[12];
#pragma unroll
        for (int i = 0; i < 3; i++)
#pragma unroll
            for (int j = 0; j < 4; j++) {
                float acc = K[i * 3 + 0] * R[0 * 4 + j];
                acc = acc + K[i * 3 + 1] * R[1 * 4 + j];
                acc = acc + K[i * 3 + 2] * R[2 * 4 + j];
                k[i * 4 + j] = acc;
            }
        float px, py;
        project_f(k, x, y, z, px, py);
        float w00, w01, w10, w11;
        int x0, x1, y0, y1;
        corner_weights_f(px, py, w00, w01, w10, w11, x0, x1, y0, y1);
        if (w00 + w01 + w10 + w11 != 0.0f) {
            size_t fb = ((size_t)bv * 32 + f) * 65536;
            float s = feat[fb + y0 * 256 + x0] * w00;
            s = s + feat[fb + y0 * 256 + x1] * w01;
            s = s + feat[fb + y1 * 256 + x0] * w10;
            s = s + feat[fb + y1 * 256 + x1] * w11;
            accm = accm + s;
            float q = s * s;
            accq = accq + q;
        }
    }
    float mean = accm * 0.25f;
    float msq  = accq * 0.25f;
    float mean2 = mean * mean;
    float var   = msq - mean2;
    size_t ob = ((size_t)b * 64 + f) * N_ + n;
    out[ob] = mean;
    out[ob + 32 * (size_t)N_] = var;
}

// ---------------------------------------------------------------------------
extern "C" void kernel_launch(void* const* d_in, const int* in_sizes, int n_in,
                              void* d_out, int out_size, void* d_ws, size_t ws_size,
                              hipStream_t stream) {
    const float* feat  = (const float*)d_in[0];
    const float* RTs   = (const float*)d_in[1];
    const float* Ks    = (const float*)d_in[2];
    const float* grids = (const float*)d_in[3];
    float* out = (float*)d_out;

    const size_t ft_bytes = (size_t)B_ * V_ * H_ * W_ * F_ * sizeof(float); // 64 MiB
    if (ws_size >= ft_bytes) {
        float* ft = (float*)d_ws;
        transpose_kernel<<<B_ * V_ * H_, 256, 0, stream>>>(feat, ft);
        sample_kernel<<<(B_ * N_) / 64, 256, 0, stream>>>(ft, RTs, Ks, grids, out);
    } else {
        naive_kernel<<<(B_ * F_ * N_) / 256, 256, 0, stream>>>(feat, RTs, Ks, grids, out);
    }
}